// Round 1
// baseline (352.980 us; speedup 1.0000x reference)
//
#include <hip/hip_runtime.h>
#include <math.h>

#define B_  32
#define NN  10
#define QS  128
#define KS  256
#define CHW  524288   // 512*32*32
#define CHW4 131072   // CHW/4

// Kernel 1: per-b attention weights.
// query[b,n,kk] = bias[kk] + sum_q qu[b,n,q]*W[kk,q]
// attn[b,i,j]   = sum_d k[b,i,d]*query[b,j,d]
// app[b,i,j]    = (i==j) ? 0 : exp(attn[b,i,j]-m_j)/sum_{r!=j} exp(attn[b,r,j]-m_j)
__global__ __launch_bounds__(256) void attn_weights_kernel(
    const float* __restrict__ qu, const float* __restrict__ kin,
    const float* __restrict__ W, const float* __restrict__ bias,
    float* __restrict__ app_out)
{
    const int b = blockIdx.x;
    const int t = threadIdx.x;

    __shared__ __align__(16) float s_qu[NN * QS];     // 1280 f
    __shared__ __align__(16) float s_k[NN * KS];      // 2560 f
    __shared__ __align__(16) float s_query[NN * KS];  // 2560 f
    __shared__ float s_attn[NN * NN];

    for (int i = t; i < NN * QS; i += 256) s_qu[i] = qu[(size_t)b * NN * QS + i];
    for (int i = t; i < NN * KS; i += 256) s_k[i]  = kin[(size_t)b * NN * KS + i];
    __syncthreads();

    // Each thread t owns output column kk = t of query (KS==256==blockDim).
    {
        float acc[NN];
        const float bv = bias[t];
        #pragma unroll
        for (int n = 0; n < NN; ++n) acc[n] = bv;
        const float4* wrow = (const float4*)(W + (size_t)t * QS);
        const float4* qu4  = (const float4*)s_qu;
        for (int q4 = 0; q4 < QS / 4; ++q4) {
            const float4 w = wrow[q4];
            #pragma unroll
            for (int n = 0; n < NN; ++n) {
                const float4 u = qu4[n * (QS / 4) + q4];
                acc[n] += w.x * u.x + w.y * u.y + w.z * u.z + w.w * u.w;
            }
        }
        #pragma unroll
        for (int n = 0; n < NN; ++n) s_query[n * KS + t] = acc[n];
    }
    __syncthreads();

    if (t < NN * NN) {
        const int i = t / NN, j = t % NN;
        float s = 0.f;
        for (int d = 0; d < KS; ++d) s += s_k[i * KS + d] * s_query[j * KS + d];
        s_attn[i * NN + j] = s;
    }
    __syncthreads();

    if (t < NN) {
        const int j = t;
        float m = -1e30f;
        #pragma unroll
        for (int i = 0; i < NN; ++i)
            if (i != j) m = fmaxf(m, s_attn[i * NN + j]);
        float denom = 0.f;
        #pragma unroll
        for (int i = 0; i < NN; ++i)
            if (i != j) denom += expf(s_attn[i * NN + j] - m);
        const float inv = 1.f / denom;
        #pragma unroll
        for (int i = 0; i < NN; ++i) {
            const float a = (i == j) ? 0.f : expf(s_attn[i * NN + j] - m) * inv;
            app_out[(size_t)b * NN * NN + i * NN + j] = a;
        }
    }
}

// Kernel 2: out[b,q,pos] = sum_k app[b,k,q] * v[b,k,pos]   (pos over CHW)
// Memory-bound streaming: read v once, write out once, float4 coalesced.
__global__ __launch_bounds__(256) void wsum_kernel(
    const float* __restrict__ v, const float* __restrict__ app,
    float* __restrict__ out)
{
    const int b = blockIdx.y;
    __shared__ float s_app[NN * NN];
    if (threadIdx.x < NN * NN) s_app[threadIdx.x] = app[(size_t)b * NN * NN + threadIdx.x];
    __syncthreads();

    const float4* vb = (const float4*)v + (size_t)b * NN * CHW4;
    float4*       ob = (float4*)out    + (size_t)b * NN * CHW4;

    const int stride = gridDim.x * blockDim.x;
    for (int pos = blockIdx.x * blockDim.x + threadIdx.x; pos < CHW4; pos += stride) {
        float4 acc[NN];
        #pragma unroll
        for (int q = 0; q < NN; ++q) acc[q] = make_float4(0.f, 0.f, 0.f, 0.f);
        #pragma unroll
        for (int kk = 0; kk < NN; ++kk) {
            const float4 vv = vb[kk * CHW4 + pos];
            #pragma unroll
            for (int q = 0; q < NN; ++q) {
                const float a = s_app[kk * NN + q];
                acc[q].x += a * vv.x;
                acc[q].y += a * vv.y;
                acc[q].z += a * vv.z;
                acc[q].w += a * vv.w;
            }
        }
        #pragma unroll
        for (int q = 0; q < NN; ++q) ob[q * CHW4 + pos] = acc[q];
    }
}

extern "C" void kernel_launch(void* const* d_in, const int* in_sizes, int n_in,
                              void* d_out, int out_size, void* d_ws, size_t ws_size,
                              hipStream_t stream) {
    const float* qu   = (const float*)d_in[0];
    const float* k    = (const float*)d_in[1];
    const float* v    = (const float*)d_in[2];
    const float* W    = (const float*)d_in[3];
    const float* bias = (const float*)d_in[4];

    float* out = (float*)d_out;
    float* app = out + (size_t)B_ * NN * CHW;  // second tuple output, flat after `out`

    attn_weights_kernel<<<B_, 256, 0, stream>>>(qu, k, W, bias, app);
    wsum_kernel<<<dim3(128, B_), 256, 0, stream>>>(v, app, out);
}

// Round 3
// 250.210 us; speedup vs baseline: 1.4107x; 1.4107x over previous
//
#include <hip/hip_runtime.h>
#include <math.h>

#define B_  32
#define NN  10
#define QS  128
#define KS  256
#define CHW  524288   // 512*32*32
#define CHW4 131072   // CHW/4  (= 512 blocks * 256 threads exactly)

typedef float f4 __attribute__((ext_vector_type(4)));

// Kernel 1: per-b attention weights (tiny; unchanged from R0).
__global__ __launch_bounds__(256) void attn_weights_kernel(
    const float* __restrict__ qu, const float* __restrict__ kin,
    const float* __restrict__ W, const float* __restrict__ bias,
    float* __restrict__ app_out)
{
    const int b = blockIdx.x;
    const int t = threadIdx.x;

    __shared__ __align__(16) float s_qu[NN * QS];
    __shared__ __align__(16) float s_k[NN * KS];
    __shared__ __align__(16) float s_query[NN * KS];
    __shared__ float s_attn[NN * NN];

    for (int i = t; i < NN * QS; i += 256) s_qu[i] = qu[(size_t)b * NN * QS + i];
    for (int i = t; i < NN * KS; i += 256) s_k[i]  = kin[(size_t)b * NN * KS + i];
    __syncthreads();

    {
        float acc[NN];
        const float bv = bias[t];
        #pragma unroll
        for (int n = 0; n < NN; ++n) acc[n] = bv;
        const float4* wrow = (const float4*)(W + (size_t)t * QS);
        const float4* qu4  = (const float4*)s_qu;
        for (int q4 = 0; q4 < QS / 4; ++q4) {
            const float4 w = wrow[q4];
            #pragma unroll
            for (int n = 0; n < NN; ++n) {
                const float4 u = qu4[n * (QS / 4) + q4];
                acc[n] += w.x * u.x + w.y * u.y + w.z * u.z + w.w * u.w;
            }
        }
        #pragma unroll
        for (int n = 0; n < NN; ++n) s_query[n * KS + t] = acc[n];
    }
    __syncthreads();

    if (t < NN * NN) {
        const int i = t / NN, j = t % NN;
        float s = 0.f;
        for (int d = 0; d < KS; ++d) s += s_k[i * KS + d] * s_query[j * KS + d];
        s_attn[i * NN + j] = s;
    }
    __syncthreads();

    if (t < NN) {
        const int j = t;
        float m = -1e30f;
        #pragma unroll
        for (int i = 0; i < NN; ++i)
            if (i != j) m = fmaxf(m, s_attn[i * NN + j]);
        float denom = 0.f;
        #pragma unroll
        for (int i = 0; i < NN; ++i)
            if (i != j) denom += expf(s_attn[i * NN + j] - m);
        const float inv = 1.f / denom;
        #pragma unroll
        for (int i = 0; i < NN; ++i) {
            const float a = (i == j) ? 0.f : expf(s_attn[i * NN + j] - m) * inv;
            app_out[(size_t)b * NN * NN + i * NN + j] = a;
        }
    }
}

// Kernel 2: out[b,q,pos] = sum_k app[b,k,q] * v[b,k,pos]
// One float4 position per thread; exact grid; nontemporal streaming.
__global__ __launch_bounds__(256) void wsum_kernel(
    const f4* __restrict__ v, const float* __restrict__ app,
    f4* __restrict__ out)
{
    const int b = blockIdx.y;
    __shared__ float s_app[NN * NN];
    if (threadIdx.x < NN * NN) s_app[threadIdx.x] = app[(size_t)b * NN * NN + threadIdx.x];
    __syncthreads();

    const int pos = blockIdx.x * 256 + threadIdx.x;   // [0, CHW4)
    const f4* vb = v   + (size_t)b * NN * CHW4 + pos;
    f4*       ob = out + (size_t)b * NN * CHW4 + pos;

    // Issue all 10 streaming loads up front (max MLP).
    f4 vv[NN];
    #pragma unroll
    for (int kk = 0; kk < NN; ++kk)
        vv[kk] = __builtin_nontemporal_load(&vb[(size_t)kk * CHW4]);

    // Per-q accumulate and store immediately (stores interleave with FMAs).
    #pragma unroll
    for (int q = 0; q < NN; ++q) {
        f4 acc = (f4)(0.f);
        #pragma unroll
        for (int kk = 0; kk < NN; ++kk) {
            const float a = s_app[kk * NN + q];
            acc.x += a * vv[kk].x;
            acc.y += a * vv[kk].y;
            acc.z += a * vv[kk].z;
            acc.w += a * vv[kk].w;
        }
        __builtin_nontemporal_store(acc, &ob[(size_t)q * CHW4]);
    }
}

extern "C" void kernel_launch(void* const* d_in, const int* in_sizes, int n_in,
                              void* d_out, int out_size, void* d_ws, size_t ws_size,
                              hipStream_t stream) {
    const float* qu   = (const float*)d_in[0];
    const float* k    = (const float*)d_in[1];
    const float* v    = (const float*)d_in[2];
    const float* W    = (const float*)d_in[3];
    const float* bias = (const float*)d_in[4];

    float* out = (float*)d_out;
    float* app = out + (size_t)B_ * NN * CHW;  // second tuple output, flat after `out`

    attn_weights_kernel<<<B_, 256, 0, stream>>>(qu, k, W, bias, app);
    wsum_kernel<<<dim3(CHW4 / 256, B_), 256, 0, stream>>>(
        (const f4*)v, app, (f4*)out);
}